// Round 11
// baseline (308.662 us; speedup 1.0000x reference)
//
#include <hip/hip_runtime.h>
#include <hip/hip_bf16.h>

#define TTOK 8192
#define DDIM 512
#define HDIM 2048
#define NEXP 8
#define RBLK 256                 // router blocks
#define RTOK (TTOK / RBLK)       // 32 tokens per router block

typedef __bf16 bf16x8 __attribute__((ext_vector_type(8)));
typedef float f32x4 __attribute__((ext_vector_type(4)));
typedef unsigned short us8 __attribute__((ext_vector_type(8)));

__device__ __forceinline__ unsigned short f2bf(float f) {
  unsigned int u = __builtin_bit_cast(unsigned int, f);
  u += 0x7fffu + ((u >> 16) & 1u);
  return (unsigned short)(u >> 16);
}

__device__ __forceinline__ void gll16(const void* g, void* l) {
  __builtin_amdgcn_global_load_lds(
      (__attribute__((address_space(1))) void*)g,
      (__attribute__((address_space(3))) void*)l, 16, 0, 0);
}

// ---------------- router: logits, top-2, gates, per-block positions; fused x->bf16 ----------------
__global__ __launch_bounds__(256) void k_router(
    const float* __restrict__ x, const float* __restrict__ rw,
    const float* __restrict__ rb, float* __restrict__ logits,
    unsigned short* __restrict__ xb,
    short* __restrict__ texp, unsigned short* __restrict__ tpos,
    float* __restrict__ tgate, int* __restrict__ blockcnt) {
  __shared__ int lcnt[NEXP];
  const int tid = threadIdx.x, wid = tid >> 6, lane = tid & 63;
  if (tid < NEXP) lcnt[tid] = 0;
  __syncthreads();
  // hoist router weights: lane covers floats [lane*8, lane*8+8)
  float4 w0[NEXP], w1[NEXP];
  float rbv[NEXP];
#pragma unroll
  for (int e = 0; e < NEXP; ++e) {
    const float4* wp = (const float4*)(rw + e * DDIM);
    w0[e] = wp[lane * 2];
    w1[e] = wp[lane * 2 + 1];
    rbv[e] = rb[e];
  }
  const int tbase = blockIdx.x * RTOK;
  for (int it = 0; it < RTOK / 4; ++it) {
    const int t = tbase + it * 4 + wid;
    const float4* xr = (const float4*)(x + (size_t)t * DDIM);
    float4 v0 = xr[lane * 2], v1 = xr[lane * 2 + 1];
    // fused bf16 conversion (replaces a separate k_cvt_x pass)
    us8 o;
    o[0] = f2bf(v0.x); o[1] = f2bf(v0.y); o[2] = f2bf(v0.z); o[3] = f2bf(v0.w);
    o[4] = f2bf(v1.x); o[5] = f2bf(v1.y); o[6] = f2bf(v1.z); o[7] = f2bf(v1.w);
    *(us8*)(xb + (size_t)t * DDIM + lane * 8) = o;
    float a[NEXP];
#pragma unroll
    for (int e = 0; e < NEXP; ++e)
      a[e] = v0.x * w0[e].x + v0.y * w0[e].y + v0.z * w0[e].z + v0.w * w0[e].w +
             v1.x * w1[e].x + v1.y * w1[e].y + v1.z * w1[e].z + v1.w * w1[e].w;
#pragma unroll
    for (int off = 32; off > 0; off >>= 1)
#pragma unroll
      for (int e = 0; e < NEXP; ++e) a[e] += __shfl_xor(a[e], off, 64);
    if (lane == 0) {
      float lg[NEXP];
#pragma unroll
      for (int e = 0; e < NEXP; ++e) lg[e] = a[e] + rbv[e];
      float4 s0, s1;
      s0.x = lg[0]; s0.y = lg[1]; s0.z = lg[2]; s0.w = lg[3];
      s1.x = lg[4]; s1.y = lg[5]; s1.z = lg[6]; s1.w = lg[7];
      ((float4*)(logits + t * NEXP))[0] = s0;
      ((float4*)(logits + t * NEXP))[1] = s1;
      int i0 = 0; float m0 = lg[0];
#pragma unroll
      for (int e = 1; e < NEXP; ++e) if (lg[e] > m0) { m0 = lg[e]; i0 = e; }
      int i1 = 0; float m1 = -3.4e38f;
#pragma unroll
      for (int e = 0; e < NEXP; ++e) if (e != i0 && lg[e] > m1) { m1 = lg[e]; i1 = e; }
      float e1 = expf(m1 - m0);
      float inv = 1.0f / (1.0f + e1);
      int p0 = atomicAdd(&lcnt[i0], 1);  // LDS atomic: block-local, cheap
      int p1 = atomicAdd(&lcnt[i1], 1);
      texp[t * 2] = (short)i0;     tpos[t * 2] = (unsigned short)p0;     tgate[t * 2] = inv;
      texp[t * 2 + 1] = (short)i1; tpos[t * 2 + 1] = (unsigned short)p1; tgate[t * 2 + 1] = e1 * inv;
    }
  }
  __syncthreads();
  if (tid < NEXP) blockcnt[blockIdx.x * NEXP + tid] = lcnt[tid];
}

// ---------------- scatter (absorbs k_offsets): prefix sums + packed lists + combine idx ----------------
// Every block redundantly computes the per-expert prefix over blockcnt (cheap), so the
// separate 1-wave k_offsets launch is gone. All blocks write identical counts/offsets.
__global__ __launch_bounds__(256) void k_scatter(
    const short* __restrict__ texp, const unsigned short* __restrict__ tpos,
    const float* __restrict__ tgate, const int* __restrict__ blockcnt,
    int* __restrict__ toklist, int* __restrict__ cidx, float* __restrict__ cgate,
    int* __restrict__ counts, int* __restrict__ offsets) {
  __shared__ int base[8][NEXP];   // bases for this block's 8 router-blocks
  __shared__ int cnt_sh[NEXP];
  __shared__ int offs_sh[NEXP];
  const int tid = threadIdx.x;
  const int b0 = blockIdx.x * 8;
  if (tid < NEXP) {
    int run = 0;
#pragma unroll 8
    for (int b = 0; b < RBLK; ++b) {
      if ((unsigned)(b - b0) < 8u) base[b - b0][tid] = run;
      run += blockcnt[b * NEXP + tid];
    }
    cnt_sh[tid] = run;
    counts[tid] = run;
  }
  __syncthreads();
  if (tid < NEXP) {
    int s = 0;
    for (int q = 0; q < tid; ++q) s += cnt_sh[q];
    offs_sh[tid] = s;
    offsets[tid] = s;
  }
  __syncthreads();
  const int t = blockIdx.x * 256 + tid;
  const int rb = (t / RTOK) - b0;
#pragma unroll
  for (int k = 0; k < 2; ++k) {
    const int e = (int)texp[t * 2 + k];
    const int pos = base[rb][e] + (int)tpos[t * 2 + k];
    toklist[e * TTOK + pos] = t;
    cidx[t * 2 + k] = offs_sh[e] + pos;
    cgate[t * 2 + k] = tgate[t * 2 + k];
  }
}

// ---------------- fused weight transpose: w1 [E][D][H]->[E][H][D], w2 [E][H][D]->[E][D][H] ----------------
__global__ void k_transpose2(const float* __restrict__ w1, const float* __restrict__ w2,
                             unsigned short* __restrict__ w1t, unsigned short* __restrict__ w2t) {
  __shared__ float tile[32][33];
  const int id = blockIdx.x;
  const float* in; unsigned short* out; int R, C, rem;
  if (id < 8192) {  // w1: R=DDIM rows, C=HDIM cols
    const int e = id >> 10; rem = id & 1023;
    R = DDIM; C = HDIM;
    in = w1 + (size_t)e * R * C; out = w1t + (size_t)e * R * C;
  } else {          // w2: R=HDIM, C=DDIM
    const int e = (id - 8192) >> 10; rem = (id - 8192) & 1023;
    R = HDIM; C = DDIM;
    in = w2 + (size_t)e * R * C; out = w2t + (size_t)e * R * C;
  }
  const int ctiles = C >> 5;
  const int c0 = (rem % ctiles) * 32, r0 = (rem / ctiles) * 32;
  const int tx = threadIdx.x, ty = threadIdx.y;
#pragma unroll
  for (int i = 0; i < 32; i += 8)
    tile[ty + i][tx] = in[(size_t)(r0 + ty + i) * C + (c0 + tx)];
  __syncthreads();
#pragma unroll
  for (int i = 0; i < 32; i += 8)
    out[(size_t)(c0 + ty + i) * R + (r0 + tx)] = f2bf(tile[tx][ty + i]);
}

// ---------------- one MFMA sub-step on buffer B (compile-time), static addresses ----------------
template <int B>
__device__ __forceinline__ void mm_step(const unsigned char* smbase,
                                        const unsigned (&aoff)[2][2][4],
                                        const unsigned (&boff)[2][2][2],
                                        f32x4 (&acc)[4][2]) {
#pragma unroll
  for (int kk = 0; kk < 2; ++kk) {
    bf16x8 af[4], bv[2];
#pragma unroll
    for (int mi = 0; mi < 4; ++mi) af[mi] = *(const bf16x8*)(smbase + aoff[B][kk][mi]);
#pragma unroll
    for (int ni = 0; ni < 2; ++ni) bv[ni] = *(const bf16x8*)(smbase + boff[B][kk][ni]);
#pragma unroll
    for (int mi = 0; mi < 4; ++mi)
#pragma unroll
      for (int ni = 0; ni < 2; ++ni)
        acc[mi][ni] = __builtin_amdgcn_mfma_f32_16x16x32_bf16(af[mi], bv[ni], acc[mi][ni], 0, 0, 0);
  }
}

// ---------------- grouped GEMM: 8-wave 128x128, BK=64, dbuf, static LDS addressing ----------------
// PHASE1: xb@w1 -> gelu(tanh-form) -> h[off+m]; PHASE2: h@w2 + b2 -> y[off+m] bf16.
// K-loop unrolled x2 over the double buffer: all 24 swizzled LDS read offsets are
// precomputed into registers; gll16 sources advance by literal offsets (fold to imm).
// Per K-step: issue next tile's stage -> compute current -> ONE barrier.
// 1D grid, expert in low 3 bits (round-robin wg->XCD => expert->XCD L2 affinity).
template <int PHASE>
__global__ __launch_bounds__(512, 4) void k_gemm(
    const unsigned short* __restrict__ A, const unsigned short* __restrict__ Bt,
    const float* __restrict__ bias, const int* __restrict__ counts,
    const int* __restrict__ offsets, const int* __restrict__ toklist,
    unsigned short* __restrict__ Out) {
  constexpr int K = (PHASE == 1) ? DDIM : HDIM;   // reduction dim
  constexpr int NN = (PHASE == 1) ? HDIM : DDIM;  // output cols
  constexpr int KB = K * 2;                       // row bytes of A/Bt
  constexpr int NX = NN / 128;                    // n-tiles (16 / 4)
  constexpr int NXSH = (PHASE == 1) ? 4 : 2;      // log2(NX)
  constexpr int NT = K / 64;                      // K-steps (8 / 32), even

  const int id = blockIdx.x;
  const int e = id & 7;
  const int p = id >> 3;
  const int cnt = counts[e];
  const int m0 = (p >> NXSH) * 128;
  if (m0 >= cnt) return;
  const int n0 = (p & (NX - 1)) * 128;
  const int off = offsets[e];

  // double buffer: [buf][A 16KB | B 16KB]
  __shared__ alignas(16) unsigned char smem[2][32768];
  unsigned char* smbase = &smem[0][0];

  const int tid = threadIdx.x;
  const int wid = tid >> 6, lane = tid & 63;

  // staging: 32 chunks of 1KB per K-tile (A: c 0..15, B: c 16..31); chunk cc covers
  // rows [cc*8, cc*8+8), 128B/row. LDS dest linear (global_load_lds); source
  // byte-in-row pre-XOR-swizzled (both-sides involution with the reads below).
  const char* src[4];
  unsigned dst[4];
#pragma unroll
  for (int i = 0; i < 4; ++i) {
    const int c = i * 8 + wid;       // 0..31
    const bool isA = c < 16;
    const int cc = isA ? c : c - 16;
    const int r = cc * 8 + (lane >> 3);
    const int cs = ((lane & 7) * 16) ^ ((r & 7) << 4);
    if (isA) {
      int mrow = m0 + r; if (mrow > cnt - 1) mrow = cnt - 1;
      if (PHASE == 1) {
        const int tok = toklist[(e << 13) + mrow];
        src[i] = (const char*)A + (size_t)tok * (DDIM * 2) + cs;
      } else {
        src[i] = (const char*)A + (size_t)(off + mrow) * KB + cs;
      }
    } else {
      src[i] = (const char*)Bt + (size_t)e * NN * KB + (size_t)(n0 + r) * KB + cs;
    }
    dst[i] = (isA ? 0u : 16384u) + cc * 1024;
  }

  // 8 waves as 2x4: wave tile 64 rows x 32 cols
  const int wr = wid >> 2, wc = wid & 3;
  const int lr = lane & 15, lk = lane >> 4;

  // precompute ALL swizzled LDS read offsets (both buffers) — loop-invariant
  unsigned aoff[2][2][4], boff[2][2][2];
#pragma unroll
  for (int b = 0; b < 2; ++b)
#pragma unroll
    for (int kk = 0; kk < 2; ++kk) {
#pragma unroll
      for (int mi = 0; mi < 4; ++mi) {
        const int r = wr * 64 + mi * 16 + lr;
        aoff[b][kk][mi] = b * 32768u + r * 128 + ((kk * 64 + lk * 16) ^ ((r & 7) << 4));
      }
#pragma unroll
      for (int ni = 0; ni < 2; ++ni) {
        const int r = wc * 32 + ni * 16 + lr;
        boff[b][kk][ni] = b * 32768u + 16384u + r * 128 + ((kk * 64 + lk * 16) ^ ((r & 7) << 4));
      }
    }

  f32x4 acc[4][2] = {};

  // prologue: stage K-tile 0 into buffer 0
#pragma unroll
  for (int i = 0; i < 4; ++i) gll16(src[i], smbase + dst[i]);
  __syncthreads();

  for (int t = 0; t < NT; t += 2) {
    // prefetch tile t+1 -> buf1 (always valid: NT even, t <= NT-2)
#pragma unroll
    for (int i = 0; i < 4; ++i) gll16(src[i] + 128, smbase + 32768u + dst[i]);
    mm_step<0>(smbase, aoff, boff, acc);
    __syncthreads();  // buf1 resident; buf0 free
    if (t + 2 < NT) {
#pragma unroll
      for (int i = 0; i < 4; ++i) gll16(src[i] + 256, smbase + dst[i]);
    }
    mm_step<1>(smbase, aoff, boff, acc);
    if (t + 2 < NT) __syncthreads();  // buf0 resident; buf1 free
#pragma unroll
    for (int i = 0; i < 4; ++i) src[i] += 256;
  }

  // epilogue: C/D layout col = lane&15, row = (lane>>4)*4 + reg
  const int lq = lane >> 4;
#pragma unroll
  for (int mi = 0; mi < 4; ++mi) {
#pragma unroll
    for (int ni = 0; ni < 2; ++ni) {
      const int n = n0 + wc * 32 + ni * 16 + lr;
      const float bv_ = bias[e * NN + n];
#pragma unroll
      for (int r2 = 0; r2 < 4; ++r2) {
        const int m = m0 + wr * 64 + mi * 16 + lq * 4 + r2;
        if (m < cnt) {
          if (PHASE == 1) {
            const float xv = acc[mi][ni][r2] + bv_;
            // tanh-form GELU: x * sigmoid(2*(sqrt(2/pi)*(x + 0.044715 x^3)))
            const float u = xv * (0.7978845608f + 0.0356774081f * xv * xv);
            const float g = xv / (1.0f + __expf(-2.0f * u));
            Out[(size_t)(off + m) * HDIM + n] = f2bf(g);
          } else {
            Out[(size_t)(off + m) * DDIM + n] = f2bf(acc[mi][ni][r2] + bv_);
          }
        }
      }
    }
  }
}

// ---------------- combine: out[t] = g0*y[idx0] + g1*y[idx1]  (coalesced, no atomics) ----------------
__global__ __launch_bounds__(256) void k_combine(const unsigned short* __restrict__ yp,
                                                 const int* __restrict__ cidx,
                                                 const float* __restrict__ cgate,
                                                 float* __restrict__ out) {
  const int t = blockIdx.x * 4 + (threadIdx.x >> 6);
  const int lane = threadIdx.x & 63;
  const int i0 = cidx[t * 2], i1 = cidx[t * 2 + 1];
  const float g0 = cgate[t * 2], g1 = cgate[t * 2 + 1];
  us8 a = *(const us8*)(yp + (size_t)i0 * DDIM + lane * 8);
  us8 b = *(const us8*)(yp + (size_t)i1 * DDIM + lane * 8);
  float o[8];
#pragma unroll
  for (int j = 0; j < 8; ++j) {
    const float va = __builtin_bit_cast(float, (unsigned)a[j] << 16);
    const float vb = __builtin_bit_cast(float, (unsigned)b[j] << 16);
    o[j] = g0 * va + g1 * vb;
  }
  float* op = out + (size_t)t * DDIM + lane * 8;
  *(float4*)op = *(float4*)o;
  *(float4*)(op + 4) = *(float4*)(o + 4);
}

extern "C" void kernel_launch(void* const* d_in, const int* in_sizes, int n_in,
                              void* d_out, int out_size, void* d_ws, size_t ws_size,
                              hipStream_t stream) {
  (void)in_sizes; (void)n_in; (void)out_size; (void)ws_size;
  const float* x  = (const float*)d_in[0];
  const float* rw = (const float*)d_in[1];
  const float* rb = (const float*)d_in[2];
  const float* w1 = (const float*)d_in[3];
  const float* b1 = (const float*)d_in[4];
  const float* w2 = (const float*)d_in[5];
  const float* b2 = (const float*)d_in[6];
  float* out = (float*)d_out;
  float* logits = out + (size_t)TTOK * DDIM;

  char* ws = (char*)d_ws;
  // workspace layout (bytes), max offset ~109.45 MB
  unsigned short* xb  = (unsigned short*)(ws + 0);          //  8,388,608
  unsigned short* w1t = (unsigned short*)(ws + 8388608);    // 16,777,216  [E][H][D] bf16
  unsigned short* w2t = (unsigned short*)(ws + 25165824);   // 16,777,216  [E][D][H] bf16
  unsigned short* h   = (unsigned short*)(ws + 41943040);   // 67,108,864  [16384][H] bf16
  int*   toklist = (int*)(ws + 109051904);                  //    262,144
  int*   cidx    = (int*)(ws + 109314048);                  //     65,536
  float* cgate   = (float*)(ws + 109379584);                //     65,536
  int*   counts  = (int*)(ws + 109445120);                  //         32
  int*   offsets = (int*)(ws + 109445152);                  //         32
  // y_packed [16384][512] bf16 ALIASES w1t (dead after k_gemm<1>, stream-ordered).
  unsigned short* yp = w1t;
  // router scratch ALIASED into the h region: consumed by k_scatter strictly
  // before k_gemm<1> writes h (stream-ordered), so no extra footprint.
  char* rsc = ws + 41943040;
  short*          texp      = (short*)(rsc + 0);            //  32,768
  unsigned short* tpos      = (unsigned short*)(rsc + 32768); // 32,768
  float*          tgate     = (float*)(rsc + 65536);        //  65,536
  int*            blockcnt  = (int*)(rsc + 131072);         //   8,192

  k_router<<<RBLK, 256, 0, stream>>>(x, rw, rb, logits, xb, texp, tpos, tgate, blockcnt);
  k_transpose2<<<16384, dim3(32, 8), 0, stream>>>(w1, w2, w1t, w2t);
  k_scatter<<<TTOK / 256, 256, 0, stream>>>(texp, tpos, tgate, blockcnt,
                                            toklist, cidx, cgate, counts, offsets);

  // 1D grids: expert in low 3 bits (expert -> XCD affinity)
  k_gemm<1><<<(HDIM / 128) * (TTOK / 128) * NEXP, 512, 0, stream>>>(
      xb, w1t, b1, counts, offsets, toklist, h);
  k_gemm<2><<<(DDIM / 128) * (TTOK / 128) * NEXP, 512, 0, stream>>>(
      h, w2t, b2, counts, offsets, nullptr, yp);
  k_combine<<<TTOK / 4, 256, 0, stream>>>(yp, cidx, cgate, out);
}

// Round 12
// 282.191 us; speedup vs baseline: 1.0938x; 1.0938x over previous
//
#include <hip/hip_runtime.h>
#include <hip/hip_bf16.h>

#define TTOK 8192
#define DDIM 512
#define HDIM 2048
#define NEXP 8
#define RBLK 256                 // router blocks
#define RTOK (TTOK / RBLK)       // 32 tokens per router block

typedef __bf16 bf16x8 __attribute__((ext_vector_type(8)));
typedef float f32x4 __attribute__((ext_vector_type(4)));
typedef unsigned short us8 __attribute__((ext_vector_type(8)));

__device__ __forceinline__ unsigned short f2bf(float f) {
  unsigned int u = __builtin_bit_cast(unsigned int, f);
  u += 0x7fffu + ((u >> 16) & 1u);
  return (unsigned short)(u >> 16);
}

__device__ __forceinline__ void gll16(const void* g, void* l) {
  __builtin_amdgcn_global_load_lds(
      (__attribute__((address_space(1))) void*)g,
      (__attribute__((address_space(3))) void*)l, 16, 0, 0);
}

// ---------------- router: logits, top-2, gates, per-block positions; fused x->bf16 ----------------
__global__ __launch_bounds__(256) void k_router(
    const float* __restrict__ x, const float* __restrict__ rw,
    const float* __restrict__ rb, float* __restrict__ logits,
    unsigned short* __restrict__ xb,
    short* __restrict__ texp, unsigned short* __restrict__ tpos,
    float* __restrict__ tgate, int* __restrict__ blockcnt) {
  __shared__ int lcnt[NEXP];
  const int tid = threadIdx.x, wid = tid >> 6, lane = tid & 63;
  if (tid < NEXP) lcnt[tid] = 0;
  __syncthreads();
  // hoist router weights: lane covers floats [lane*8, lane*8+8)
  float4 w0[NEXP], w1[NEXP];
  float rbv[NEXP];
#pragma unroll
  for (int e = 0; e < NEXP; ++e) {
    const float4* wp = (const float4*)(rw + e * DDIM);
    w0[e] = wp[lane * 2];
    w1[e] = wp[lane * 2 + 1];
    rbv[e] = rb[e];
  }
  const int tbase = blockIdx.x * RTOK;
  for (int it = 0; it < RTOK / 4; ++it) {
    const int t = tbase + it * 4 + wid;
    const float4* xr = (const float4*)(x + (size_t)t * DDIM);
    float4 v0 = xr[lane * 2], v1 = xr[lane * 2 + 1];
    // fused bf16 conversion (replaces a separate k_cvt_x pass)
    us8 o;
    o[0] = f2bf(v0.x); o[1] = f2bf(v0.y); o[2] = f2bf(v0.z); o[3] = f2bf(v0.w);
    o[4] = f2bf(v1.x); o[5] = f2bf(v1.y); o[6] = f2bf(v1.z); o[7] = f2bf(v1.w);
    *(us8*)(xb + (size_t)t * DDIM + lane * 8) = o;
    float a[NEXP];
#pragma unroll
    for (int e = 0; e < NEXP; ++e)
      a[e] = v0.x * w0[e].x + v0.y * w0[e].y + v0.z * w0[e].z + v0.w * w0[e].w +
             v1.x * w1[e].x + v1.y * w1[e].y + v1.z * w1[e].z + v1.w * w1[e].w;
#pragma unroll
    for (int off = 32; off > 0; off >>= 1)
#pragma unroll
      for (int e = 0; e < NEXP; ++e) a[e] += __shfl_xor(a[e], off, 64);
    if (lane == 0) {
      float lg[NEXP];
#pragma unroll
      for (int e = 0; e < NEXP; ++e) lg[e] = a[e] + rbv[e];
      float4 s0, s1;
      s0.x = lg[0]; s0.y = lg[1]; s0.z = lg[2]; s0.w = lg[3];
      s1.x = lg[4]; s1.y = lg[5]; s1.z = lg[6]; s1.w = lg[7];
      ((float4*)(logits + t * NEXP))[0] = s0;
      ((float4*)(logits + t * NEXP))[1] = s1;
      int i0 = 0; float m0 = lg[0];
#pragma unroll
      for (int e = 1; e < NEXP; ++e) if (lg[e] > m0) { m0 = lg[e]; i0 = e; }
      int i1 = 0; float m1 = -3.4e38f;
#pragma unroll
      for (int e = 0; e < NEXP; ++e) if (e != i0 && lg[e] > m1) { m1 = lg[e]; i1 = e; }
      float e1 = expf(m1 - m0);
      float inv = 1.0f / (1.0f + e1);
      int p0 = atomicAdd(&lcnt[i0], 1);  // LDS atomic: block-local, cheap
      int p1 = atomicAdd(&lcnt[i1], 1);
      texp[t * 2] = (short)i0;     tpos[t * 2] = (unsigned short)p0;     tgate[t * 2] = inv;
      texp[t * 2 + 1] = (short)i1; tpos[t * 2 + 1] = (unsigned short)p1; tgate[t * 2 + 1] = e1 * inv;
    }
  }
  __syncthreads();
  if (tid < NEXP) blockcnt[blockIdx.x * NEXP + tid] = lcnt[tid];
}

// ---------------- per-block bases via parallel shfl prefix-scan (8 waves, 1 block) ----------------
__global__ __launch_bounds__(512) void k_offsets(const int* __restrict__ blockcnt,
                                                 int* __restrict__ blockbase,
                                                 int* __restrict__ counts,
                                                 int* __restrict__ offsets) {
  __shared__ int csh[NEXP];
  const int e = threadIdx.x >> 6, lane = threadIdx.x & 63;
  int carry = 0;
#pragma unroll
  for (int c = 0; c < RBLK; c += 64) {
    int v = blockcnt[(c + lane) * NEXP + e];
    int s = v;
#pragma unroll
    for (int o = 1; o < 64; o <<= 1) {
      int u = __shfl_up(s, o, 64);
      if (lane >= o) s += u;
    }
    blockbase[(c + lane) * NEXP + e] = carry + s - v;  // exclusive prefix
    carry += __shfl(s, 63, 64);
  }
  if (lane == 0) csh[e] = carry;
  __syncthreads();
  if (threadIdx.x < NEXP) {
    int s = 0;
    for (int q = 0; q < (int)threadIdx.x; ++q) s += csh[q];
    offsets[threadIdx.x] = s;
    counts[threadIdx.x] = csh[threadIdx.x];
  }
}

// ---------------- scatter: packed token lists + per-token combine indices ----------------
// toklist: per-expert segments (stride TTOK), position = blockbase+tpos.
// cidx[t*2+k] = GLOBAL packed row (offsets[e]+pos) for k_combine; cgate = gate.
__global__ void k_scatter(const short* __restrict__ texp, const unsigned short* __restrict__ tpos,
                          const float* __restrict__ tgate, const int* __restrict__ blockbase,
                          const int* __restrict__ offsets,
                          int* __restrict__ toklist, int* __restrict__ cidx,
                          float* __restrict__ cgate) {
  const int t = blockIdx.x * 256 + threadIdx.x;
  const int b = t / RTOK;
#pragma unroll
  for (int k = 0; k < 2; ++k) {
    const int e = (int)texp[t * 2 + k];
    const int pos = blockbase[b * NEXP + e] + (int)tpos[t * 2 + k];
    toklist[e * TTOK + pos] = t;
    cidx[t * 2 + k] = offsets[e] + pos;
    cgate[t * 2 + k] = tgate[t * 2 + k];
  }
}

// ---------------- fused weight transpose: w1 [E][D][H]->[E][H][D], w2 [E][H][D]->[E][D][H] ----------------
__global__ void k_transpose2(const float* __restrict__ w1, const float* __restrict__ w2,
                             unsigned short* __restrict__ w1t, unsigned short* __restrict__ w2t) {
  __shared__ float tile[32][33];
  const int id = blockIdx.x;
  const float* in; unsigned short* out; int R, C, rem;
  if (id < 8192) {  // w1: R=DDIM rows, C=HDIM cols
    const int e = id >> 10; rem = id & 1023;
    R = DDIM; C = HDIM;
    in = w1 + (size_t)e * R * C; out = w1t + (size_t)e * R * C;
  } else {          // w2: R=HDIM, C=DDIM
    const int e = (id - 8192) >> 10; rem = (id - 8192) & 1023;
    R = HDIM; C = DDIM;
    in = w2 + (size_t)e * R * C; out = w2t + (size_t)e * R * C;
  }
  const int ctiles = C >> 5;
  const int c0 = (rem % ctiles) * 32, r0 = (rem / ctiles) * 32;
  const int tx = threadIdx.x, ty = threadIdx.y;
#pragma unroll
  for (int i = 0; i < 32; i += 8)
    tile[ty + i][tx] = in[(size_t)(r0 + ty + i) * C + (c0 + tx)];
  __syncthreads();
#pragma unroll
  for (int i = 0; i < 32; i += 8)
    out[(size_t)(c0 + ty + i) * R + (r0 + tx)] = f2bf(tile[tx][ty + i]);
}

// ---------------- one MFMA sub-step on buffer B (compile-time), static addresses ----------------
template <int B>
__device__ __forceinline__ void mm_step(const unsigned char* smbase,
                                        const unsigned (&aoff)[2][2][4],
                                        const unsigned (&boff)[2][2][2],
                                        f32x4 (&acc)[4][2]) {
#pragma unroll
  for (int kk = 0; kk < 2; ++kk) {
    bf16x8 af[4], bv[2];
#pragma unroll
    for (int mi = 0; mi < 4; ++mi) af[mi] = *(const bf16x8*)(smbase + aoff[B][kk][mi]);
#pragma unroll
    for (int ni = 0; ni < 2; ++ni) bv[ni] = *(const bf16x8*)(smbase + boff[B][kk][ni]);
#pragma unroll
    for (int mi = 0; mi < 4; ++mi)
#pragma unroll
      for (int ni = 0; ni < 2; ++ni)
        acc[mi][ni] = __builtin_amdgcn_mfma_f32_16x16x32_bf16(af[mi], bv[ni], acc[mi][ni], 0, 0, 0);
  }
}

// ---------------- grouped GEMM: 8-wave 128x128, BK=64, COUNTED-VMCNT 2-deep pipeline (T4) ----------------
// PHASE1: xb@w1 -> gelu(tanh-form) -> h[off+m]; PHASE2: h@w2 + b2 -> y[off+m] bf16.
// Prologue stages tiles 0,1 (8 loads/thread in flight). Per step:
//   s_waitcnt vmcnt(4)   <- tile t resident, tile t+1 still flying (never drain to 0)
//   s_barrier; MFMA(buf t&1); s_barrier; STAGE(tile t+2 -> buf t&1)
// 1D grid, expert in low 3 bits (round-robin wg->XCD => expert->XCD L2 affinity).
template <int PHASE>
__global__ __launch_bounds__(512, 4) void k_gemm(
    const unsigned short* __restrict__ A, const unsigned short* __restrict__ Bt,
    const float* __restrict__ bias, const int* __restrict__ counts,
    const int* __restrict__ offsets, const int* __restrict__ toklist,
    unsigned short* __restrict__ Out) {
  constexpr int K = (PHASE == 1) ? DDIM : HDIM;   // reduction dim
  constexpr int NN = (PHASE == 1) ? HDIM : DDIM;  // output cols
  constexpr int KB = K * 2;                       // row bytes of A/Bt
  constexpr int NX = NN / 128;                    // n-tiles (16 / 4)
  constexpr int NXSH = (PHASE == 1) ? 4 : 2;      // log2(NX)
  constexpr int NT = K / 64;                      // K-steps (8 / 32), even

  const int id = blockIdx.x;
  const int e = id & 7;
  const int p = id >> 3;
  const int cnt = counts[e];
  const int m0 = (p >> NXSH) * 128;
  if (m0 >= cnt) return;
  const int n0 = (p & (NX - 1)) * 128;
  const int off = offsets[e];

  // double buffer: [buf][A 16KB | B 16KB]
  __shared__ alignas(16) unsigned char smem[2][32768];
  unsigned char* smbase = &smem[0][0];

  const int tid = threadIdx.x;
  const int wid = tid >> 6, lane = tid & 63;

  // staging: 32 chunks of 1KB per K-tile (A: c 0..15, B: c 16..31); chunk cc covers
  // rows [cc*8, cc*8+8), 128B/row. LDS dest linear (global_load_lds); source
  // byte-in-row pre-XOR-swizzled (both-sides involution with the reads below).
  const char* src[4];
  unsigned dst[4];
#pragma unroll
  for (int i = 0; i < 4; ++i) {
    const int c = i * 8 + wid;       // 0..31
    const bool isA = c < 16;
    const int cc = isA ? c : c - 16;
    const int r = cc * 8 + (lane >> 3);
    const int cs = ((lane & 7) * 16) ^ ((r & 7) << 4);
    if (isA) {
      int mrow = m0 + r; if (mrow > cnt - 1) mrow = cnt - 1;
      if (PHASE == 1) {
        const int tok = toklist[(e << 13) + mrow];
        src[i] = (const char*)A + (size_t)tok * (DDIM * 2) + cs;
      } else {
        src[i] = (const char*)A + (size_t)(off + mrow) * KB + cs;
      }
    } else {
      src[i] = (const char*)Bt + (size_t)e * NN * KB + (size_t)(n0 + r) * KB + cs;
    }
    dst[i] = (isA ? 0u : 16384u) + cc * 1024;
  }

  // 8 waves as 2x4: wave tile 64 rows x 32 cols
  const int wr = wid >> 2, wc = wid & 3;
  const int lr = lane & 15, lk = lane >> 4;

  // precompute swizzled LDS read offsets (both buffers) — loop-invariant
  unsigned aoff[2][2][4], boff[2][2][2];
#pragma unroll
  for (int b = 0; b < 2; ++b)
#pragma unroll
    for (int kk = 0; kk < 2; ++kk) {
#pragma unroll
      for (int mi = 0; mi < 4; ++mi) {
        const int r = wr * 64 + mi * 16 + lr;
        aoff[b][kk][mi] = b * 32768u + r * 128 + ((kk * 64 + lk * 16) ^ ((r & 7) << 4));
      }
#pragma unroll
      for (int ni = 0; ni < 2; ++ni) {
        const int r = wc * 32 + ni * 16 + lr;
        boff[b][kk][ni] = b * 32768u + 16384u + r * 128 + ((kk * 64 + lk * 16) ^ ((r & 7) << 4));
      }
    }

  f32x4 acc[4][2] = {};

  // prologue: stage tile 0 -> buf0, tile 1 -> buf1 (NT >= 2 always)
#pragma unroll
  for (int i = 0; i < 4; ++i) gll16(src[i], smbase + dst[i]);
#pragma unroll
  for (int i = 0; i < 4; ++i) gll16(src[i] + 128, smbase + 32768u + dst[i]);

  for (int t = 0; t < NT; ++t) {
    if (t + 1 < NT) asm volatile("s_waitcnt vmcnt(4)" ::: "memory");
    else            asm volatile("s_waitcnt vmcnt(0)" ::: "memory");
    __builtin_amdgcn_s_barrier();
    __builtin_amdgcn_sched_barrier(0);
    if (t & 1) mm_step<1>(smbase, aoff, boff, acc);
    else       mm_step<0>(smbase, aoff, boff, acc);
    if (t + 2 < NT) {
      __builtin_amdgcn_s_barrier();       // all waves done reading buf[t&1]
      __builtin_amdgcn_sched_barrier(0);
      const int kb = (t + 2) * 128;
      const unsigned bb = (t & 1) ? 32768u : 0u;
#pragma unroll
      for (int i = 0; i < 4; ++i) gll16(src[i] + kb, smbase + bb + dst[i]);
    }
  }

  // epilogue: C/D layout col = lane&15, row = (lane>>4)*4 + reg
  const int lq = lane >> 4;
#pragma unroll
  for (int mi = 0; mi < 4; ++mi) {
#pragma unroll
    for (int ni = 0; ni < 2; ++ni) {
      const int n = n0 + wc * 32 + ni * 16 + lr;
      const float bv_ = bias[e * NN + n];
#pragma unroll
      for (int r2 = 0; r2 < 4; ++r2) {
        const int m = m0 + wr * 64 + mi * 16 + lq * 4 + r2;
        if (m < cnt) {
          if (PHASE == 1) {
            const float xv = acc[mi][ni][r2] + bv_;
            // tanh-form GELU: x * sigmoid(2*(sqrt(2/pi)*(x + 0.044715 x^3)))
            const float u = xv * (0.7978845608f + 0.0356774081f * xv * xv);
            const float g = xv / (1.0f + __expf(-2.0f * u));
            Out[(size_t)(off + m) * HDIM + n] = f2bf(g);
          } else {
            Out[(size_t)(off + m) * DDIM + n] = f2bf(acc[mi][ni][r2] + bv_);
          }
        }
      }
    }
  }
}

// ---------------- combine: out[t] = g0*y[idx0] + g1*y[idx1]  (coalesced, no atomics) ----------------
__global__ __launch_bounds__(256) void k_combine(const unsigned short* __restrict__ yp,
                                                 const int* __restrict__ cidx,
                                                 const float* __restrict__ cgate,
                                                 float* __restrict__ out) {
  const int t = blockIdx.x * 4 + (threadIdx.x >> 6);
  const int lane = threadIdx.x & 63;
  const int i0 = cidx[t * 2], i1 = cidx[t * 2 + 1];
  const float g0 = cgate[t * 2], g1 = cgate[t * 2 + 1];
  us8 a = *(const us8*)(yp + (size_t)i0 * DDIM + lane * 8);
  us8 b = *(const us8*)(yp + (size_t)i1 * DDIM + lane * 8);
  float o[8];
#pragma unroll
  for (int j = 0; j < 8; ++j) {
    const float va = __builtin_bit_cast(float, (unsigned)a[j] << 16);
    const float vb = __builtin_bit_cast(float, (unsigned)b[j] << 16);
    o[j] = g0 * va + g1 * vb;
  }
  float* op = out + (size_t)t * DDIM + lane * 8;
  *(float4*)op = *(float4*)o;
  *(float4*)(op + 4) = *(float4*)(o + 4);
}

extern "C" void kernel_launch(void* const* d_in, const int* in_sizes, int n_in,
                              void* d_out, int out_size, void* d_ws, size_t ws_size,
                              hipStream_t stream) {
  (void)in_sizes; (void)n_in; (void)out_size; (void)ws_size;
  const float* x  = (const float*)d_in[0];
  const float* rw = (const float*)d_in[1];
  const float* rb = (const float*)d_in[2];
  const float* w1 = (const float*)d_in[3];
  const float* b1 = (const float*)d_in[4];
  const float* w2 = (const float*)d_in[5];
  const float* b2 = (const float*)d_in[6];
  float* out = (float*)d_out;
  float* logits = out + (size_t)TTOK * DDIM;

  char* ws = (char*)d_ws;
  // workspace layout (bytes), max offset ~109.45 MB
  unsigned short* xb  = (unsigned short*)(ws + 0);          //  8,388,608
  unsigned short* w1t = (unsigned short*)(ws + 8388608);    // 16,777,216  [E][H][D] bf16
  unsigned short* w2t = (unsigned short*)(ws + 25165824);   // 16,777,216  [E][D][H] bf16
  unsigned short* h   = (unsigned short*)(ws + 41943040);   // 67,108,864  [16384][H] bf16
  int*   toklist = (int*)(ws + 109051904);                  //    262,144
  int*   cidx    = (int*)(ws + 109314048);                  //     65,536
  float* cgate   = (float*)(ws + 109379584);                //     65,536
  int*   counts  = (int*)(ws + 109445120);                  //         32
  int*   offsets = (int*)(ws + 109445152);                  //         32
  // y_packed [16384][512] bf16 ALIASES w1t (dead after k_gemm<1>, stream-ordered).
  unsigned short* yp = w1t;
  // router scratch ALIASED into the h region: consumed by k_scatter strictly
  // before k_gemm<1> writes h (stream-ordered), so no extra footprint.
  char* rsc = ws + 41943040;
  short*          texp      = (short*)(rsc + 0);            //  32,768
  unsigned short* tpos      = (unsigned short*)(rsc + 32768); // 32,768
  float*          tgate     = (float*)(rsc + 65536);        //  65,536
  int*            blockcnt  = (int*)(rsc + 131072);         //   8,192
  int*            blockbase = (int*)(rsc + 139264);         //   8,192

  k_router<<<RBLK, 256, 0, stream>>>(x, rw, rb, logits, xb, texp, tpos, tgate, blockcnt);
  k_transpose2<<<16384, dim3(32, 8), 0, stream>>>(w1, w2, w1t, w2t);
  k_offsets<<<1, 512, 0, stream>>>(blockcnt, blockbase, counts, offsets);
  k_scatter<<<TTOK / 256, 256, 0, stream>>>(texp, tpos, tgate, blockbase, offsets,
                                            toklist, cidx, cgate);

  // 1D grids: expert in low 3 bits (expert -> XCD affinity)
  k_gemm<1><<<(HDIM / 128) * (TTOK / 128) * NEXP, 512, 0, stream>>>(
      xb, w1t, b1, counts, offsets, toklist, h);
  k_gemm<2><<<(DDIM / 128) * (TTOK / 128) * NEXP, 512, 0, stream>>>(
      h, w2t, b2, counts, offsets, nullptr, yp);
  k_combine<<<TTOK / 4, 256, 0, stream>>>(yp, cidx, cgate, out);
}

// Round 13
// 267.198 us; speedup vs baseline: 1.1552x; 1.0561x over previous
//
#include <hip/hip_runtime.h>
#include <hip/hip_bf16.h>

#define TTOK 8192
#define DDIM 512
#define HDIM 2048
#define NEXP 8
#define RBLK 256                 // router blocks
#define RTOK (TTOK / RBLK)       // 32 tokens per router block

typedef __bf16 bf16x8 __attribute__((ext_vector_type(8)));
typedef float f32x4 __attribute__((ext_vector_type(4)));
typedef unsigned short us8 __attribute__((ext_vector_type(8)));

__device__ __forceinline__ unsigned short f2bf(float f) {
  unsigned int u = __builtin_bit_cast(unsigned int, f);
  u += 0x7fffu + ((u >> 16) & 1u);
  return (unsigned short)(u >> 16);
}

__device__ __forceinline__ void gll16(const void* g, void* l) {
  __builtin_amdgcn_global_load_lds(
      (__attribute__((address_space(1))) void*)g,
      (__attribute__((address_space(3))) void*)l, 16, 0, 0);
}

// ---------------- fused router + weight transpose ----------------
// Blocks 0..RBLK-1: router (logits, top-2, gates, per-block positions, x->bf16).
// Blocks RBLK..RBLK+16383: 32x32 transpose tiles of w1 / w2 (fp32 -> bf16 [N][K]).
// Independent work overlapped in one dispatch.
__global__ __launch_bounds__(256) void k_routrans(
    const float* __restrict__ x, const float* __restrict__ rw,
    const float* __restrict__ rb, float* __restrict__ logits,
    unsigned short* __restrict__ xb,
    short* __restrict__ texp, unsigned short* __restrict__ tpos,
    float* __restrict__ tgate, int* __restrict__ blockcnt,
    const float* __restrict__ w1, const float* __restrict__ w2,
    unsigned short* __restrict__ w1t, unsigned short* __restrict__ w2t) {
  const int tid = threadIdx.x;
  if (blockIdx.x >= RBLK) {
    // ---- transpose path ----
    __shared__ float tile[32][33];
    const int id = blockIdx.x - RBLK;
    const float* in; unsigned short* out; int R, C, rem;
    if (id < 8192) {  // w1: R=DDIM rows, C=HDIM cols
      const int e = id >> 10; rem = id & 1023;
      R = DDIM; C = HDIM;
      in = w1 + (size_t)e * R * C; out = w1t + (size_t)e * R * C;
    } else {          // w2: R=HDIM, C=DDIM
      const int e = (id - 8192) >> 10; rem = (id - 8192) & 1023;
      R = HDIM; C = DDIM;
      in = w2 + (size_t)e * R * C; out = w2t + (size_t)e * R * C;
    }
    const int ctiles = C >> 5;
    const int c0 = (rem % ctiles) * 32, r0 = (rem / ctiles) * 32;
    const int tx = tid & 31, ty = tid >> 5;
#pragma unroll
    for (int i = 0; i < 32; i += 8)
      tile[ty + i][tx] = in[(size_t)(r0 + ty + i) * C + (c0 + tx)];
    __syncthreads();
#pragma unroll
    for (int i = 0; i < 32; i += 8)
      out[(size_t)(c0 + ty + i) * R + (r0 + tx)] = f2bf(tile[tx][ty + i]);
    return;
  }
  // ---- router path ----
  __shared__ int lcnt[NEXP];
  const int wid = tid >> 6, lane = tid & 63;
  if (tid < NEXP) lcnt[tid] = 0;
  __syncthreads();
  float4 w0r[NEXP], w1r[NEXP];
  float rbv[NEXP];
#pragma unroll
  for (int e = 0; e < NEXP; ++e) {
    const float4* wp = (const float4*)(rw + e * DDIM);
    w0r[e] = wp[lane * 2];
    w1r[e] = wp[lane * 2 + 1];
    rbv[e] = rb[e];
  }
  const int tbase = blockIdx.x * RTOK;
  for (int it = 0; it < RTOK / 4; ++it) {
    const int t = tbase + it * 4 + wid;
    const float4* xr = (const float4*)(x + (size_t)t * DDIM);
    float4 v0 = xr[lane * 2], v1 = xr[lane * 2 + 1];
    us8 o;
    o[0] = f2bf(v0.x); o[1] = f2bf(v0.y); o[2] = f2bf(v0.z); o[3] = f2bf(v0.w);
    o[4] = f2bf(v1.x); o[5] = f2bf(v1.y); o[6] = f2bf(v1.z); o[7] = f2bf(v1.w);
    *(us8*)(xb + (size_t)t * DDIM + lane * 8) = o;
    float a[NEXP];
#pragma unroll
    for (int e = 0; e < NEXP; ++e)
      a[e] = v0.x * w0r[e].x + v0.y * w0r[e].y + v0.z * w0r[e].z + v0.w * w0r[e].w +
             v1.x * w1r[e].x + v1.y * w1r[e].y + v1.z * w1r[e].z + v1.w * w1r[e].w;
#pragma unroll
    for (int off = 32; off > 0; off >>= 1)
#pragma unroll
      for (int e = 0; e < NEXP; ++e) a[e] += __shfl_xor(a[e], off, 64);
    if (lane == 0) {
      float lg[NEXP];
#pragma unroll
      for (int e = 0; e < NEXP; ++e) lg[e] = a[e] + rbv[e];
      float4 s0, s1;
      s0.x = lg[0]; s0.y = lg[1]; s0.z = lg[2]; s0.w = lg[3];
      s1.x = lg[4]; s1.y = lg[5]; s1.z = lg[6]; s1.w = lg[7];
      ((float4*)(logits + t * NEXP))[0] = s0;
      ((float4*)(logits + t * NEXP))[1] = s1;
      int i0 = 0; float m0 = lg[0];
#pragma unroll
      for (int e = 1; e < NEXP; ++e) if (lg[e] > m0) { m0 = lg[e]; i0 = e; }
      int i1 = 0; float m1 = -3.4e38f;
#pragma unroll
      for (int e = 0; e < NEXP; ++e) if (e != i0 && lg[e] > m1) { m1 = lg[e]; i1 = e; }
      float e1 = expf(m1 - m0);
      float inv = 1.0f / (1.0f + e1);
      int p0 = atomicAdd(&lcnt[i0], 1);
      int p1 = atomicAdd(&lcnt[i1], 1);
      texp[t * 2] = (short)i0;     tpos[t * 2] = (unsigned short)p0;     tgate[t * 2] = inv;
      texp[t * 2 + 1] = (short)i1; tpos[t * 2 + 1] = (unsigned short)p1; tgate[t * 2 + 1] = e1 * inv;
    }
  }
  __syncthreads();
  if (tid < NEXP) blockcnt[blockIdx.x * NEXP + tid] = lcnt[tid];
}

// ---------------- per-block bases via parallel shfl prefix-scan (8 waves, 1 block) ----------------
__global__ __launch_bounds__(512) void k_offsets(const int* __restrict__ blockcnt,
                                                 int* __restrict__ blockbase,
                                                 int* __restrict__ counts,
                                                 int* __restrict__ offsets) {
  __shared__ int csh[NEXP];
  const int e = threadIdx.x >> 6, lane = threadIdx.x & 63;
  int carry = 0;
#pragma unroll
  for (int c = 0; c < RBLK; c += 64) {
    int v = blockcnt[(c + lane) * NEXP + e];
    int s = v;
#pragma unroll
    for (int o = 1; o < 64; o <<= 1) {
      int u = __shfl_up(s, o, 64);
      if (lane >= o) s += u;
    }
    blockbase[(c + lane) * NEXP + e] = carry + s - v;  // exclusive prefix
    carry += __shfl(s, 63, 64);
  }
  if (lane == 0) csh[e] = carry;
  __syncthreads();
  if (threadIdx.x < NEXP) {
    int s = 0;
    for (int q = 0; q < (int)threadIdx.x; ++q) s += csh[q];
    offsets[threadIdx.x] = s;
    counts[threadIdx.x] = csh[threadIdx.x];
  }
}

// ---------------- scatter: packed token lists + per-token combine indices ----------------
__global__ void k_scatter(const short* __restrict__ texp, const unsigned short* __restrict__ tpos,
                          const float* __restrict__ tgate, const int* __restrict__ blockbase,
                          const int* __restrict__ offsets,
                          int* __restrict__ toklist, int* __restrict__ cidx,
                          float* __restrict__ cgate) {
  const int t = blockIdx.x * 256 + threadIdx.x;
  const int b = t / RTOK;
#pragma unroll
  for (int k = 0; k < 2; ++k) {
    const int e = (int)texp[t * 2 + k];
    const int pos = blockbase[b * NEXP + e] + (int)tpos[t * 2 + k];
    toklist[e * TTOK + pos] = t;
    cidx[t * 2 + k] = offsets[e] + pos;
    cgate[t * 2 + k] = tgate[t * 2 + k];
  }
}

// ---------------- GEMM1: xb@w1 -> gelu -> h. 128x256 block, 8 waves of 64x64, 48KB LDS ----------------
// Single-buffer drain loop (r9-proven); 3 blocks/CU (24 waves/CU) does the latency hiding.
// Wave tile 64x64 => MFMA:ds_read = 2:1 (LDS bytes/FLOP 0.67x of the 64x32 tiling).
// 1D grid, expert in low 3 bits (round-robin wg->XCD => expert->XCD L2 affinity).
__global__ __launch_bounds__(512, 4) void k_gemm1(
    const unsigned short* __restrict__ A, const unsigned short* __restrict__ Bt,
    const float* __restrict__ bias, const int* __restrict__ counts,
    const int* __restrict__ offsets, const int* __restrict__ toklist,
    unsigned short* __restrict__ Out) {
  constexpr int K = DDIM;          // 512
  constexpr int NN = HDIM;         // 2048
  constexpr int NX = NN / 256;     // 8 n-tiles
  constexpr int NT = K / 64;       // 8 K-steps

  const int id = blockIdx.x;
  const int e = id & 7;
  const int p = id >> 3;
  const int cnt = counts[e];
  const int m0 = (p >> 3) * 128;
  if (m0 >= cnt) return;
  const int n0 = (p & (NX - 1)) * 256;
  const int off = offsets[e];

  __shared__ alignas(16) unsigned char smem[49152];  // A 16KB | B 32KB

  const int tid = threadIdx.x;
  const int wid = tid >> 6, lane = tid & 63;

  // staging: 48 chunks of 1KB (A: 0..15 -> rows 0..127; B: 16..47 -> rows 0..255).
  // Thread handles chunks c = i*8 + wid, i=0..5. LDS dest linear (global_load_lds);
  // source byte-in-row pre-XOR-swizzled (both-sides involution with reads below).
  const char* src[6];
  unsigned dst[6];
#pragma unroll
  for (int i = 0; i < 6; ++i) {
    const int c = i * 8 + wid;       // 0..47
    const bool isA = c < 16;
    const int cc = isA ? c : c - 16;
    const int r = cc * 8 + (lane >> 3);
    const int cs = ((lane & 7) * 16) ^ ((r & 7) << 4);
    if (isA) {
      int mrow = m0 + r; if (mrow > cnt - 1) mrow = cnt - 1;
      const int tok = toklist[(e << 13) + mrow];
      src[i] = (const char*)A + (size_t)tok * (DDIM * 2) + cs;
    } else {
      src[i] = (const char*)Bt + (size_t)e * NN * (K * 2) + (size_t)(n0 + r) * (K * 2) + cs;
    }
    dst[i] = (isA ? 0u : 16384u) + cc * 1024;
  }

  // 8 waves as 2x4: wave tile 64 rows x 64 cols
  const int wr = wid >> 2, wc = wid & 3;
  const int lr = lane & 15, lk = lane >> 4;

  f32x4 acc[4][4] = {};

  for (int t = 0; t < NT; ++t) {
    const int kb = t * 128;
#pragma unroll
    for (int i = 0; i < 6; ++i) gll16(src[i] + kb, smem + dst[i]);
    __syncthreads();
#pragma unroll
    for (int kk = 0; kk < 2; ++kk) {
      bf16x8 af[4], bv[4];
#pragma unroll
      for (int mi = 0; mi < 4; ++mi) {
        const int r = wr * 64 + mi * 16 + lr;
        const int byteo = r * 128 + ((kk * 64 + lk * 16) ^ ((r & 7) << 4));
        af[mi] = *(const bf16x8*)(smem + byteo);
      }
#pragma unroll
      for (int ni = 0; ni < 4; ++ni) {
        const int r = wc * 64 + ni * 16 + lr;
        const int byteo = 16384 + r * 128 + ((kk * 64 + lk * 16) ^ ((r & 7) << 4));
        bv[ni] = *(const bf16x8*)(smem + byteo);
      }
#pragma unroll
      for (int mi = 0; mi < 4; ++mi)
#pragma unroll
        for (int ni = 0; ni < 4; ++ni)
          acc[mi][ni] = __builtin_amdgcn_mfma_f32_16x16x32_bf16(af[mi], bv[ni], acc[mi][ni], 0, 0, 0);
    }
    if (t + 1 < NT) __syncthreads();
  }

  // epilogue: C/D layout col = lane&15, row = (lane>>4)*4 + reg
  const int lq = lane >> 4;
#pragma unroll
  for (int mi = 0; mi < 4; ++mi) {
#pragma unroll
    for (int ni = 0; ni < 4; ++ni) {
      const int n = n0 + wc * 64 + ni * 16 + lr;
      const float bv_ = bias[e * NN + n];
#pragma unroll
      for (int r2 = 0; r2 < 4; ++r2) {
        const int m = m0 + wr * 64 + mi * 16 + lq * 4 + r2;
        if (m < cnt) {
          const float xv = acc[mi][ni][r2] + bv_;
          // tanh-form GELU
          const float u = xv * (0.7978845608f + 0.0356774081f * xv * xv);
          const float g = xv / (1.0f + __expf(-2.0f * u));
          Out[(size_t)(off + m) * HDIM + n] = f2bf(g);
        }
      }
    }
  }
}

// ---------------- one MFMA sub-step on buffer B (compile-time), static addresses ----------------
template <int B>
__device__ __forceinline__ void mm_step(const unsigned char* smbase,
                                        const unsigned (&aoff)[2][2][4],
                                        const unsigned (&boff)[2][2][2],
                                        f32x4 (&acc)[4][2]) {
#pragma unroll
  for (int kk = 0; kk < 2; ++kk) {
    bf16x8 af[4], bv[2];
#pragma unroll
    for (int mi = 0; mi < 4; ++mi) af[mi] = *(const bf16x8*)(smbase + aoff[B][kk][mi]);
#pragma unroll
    for (int ni = 0; ni < 2; ++ni) bv[ni] = *(const bf16x8*)(smbase + boff[B][kk][ni]);
#pragma unroll
    for (int mi = 0; mi < 4; ++mi)
#pragma unroll
      for (int ni = 0; ni < 2; ++ni)
        acc[mi][ni] = __builtin_amdgcn_mfma_f32_16x16x32_bf16(af[mi], bv[ni], acc[mi][ni], 0, 0, 0);
  }
}

// ---------------- GEMM2: h@w2 + b2 -> y (r12 structure: 8-wave 128x128, counted vmcnt) ----------------
__global__ __launch_bounds__(512, 4) void k_gemm2(
    const unsigned short* __restrict__ A, const unsigned short* __restrict__ Bt,
    const float* __restrict__ bias, const int* __restrict__ counts,
    const int* __restrict__ offsets, unsigned short* __restrict__ Out) {
  constexpr int K = HDIM;          // 2048
  constexpr int NN = DDIM;         // 512
  constexpr int KB = K * 2;
  constexpr int NX = NN / 128;     // 4
  constexpr int NT = K / 64;       // 32

  const int id = blockIdx.x;
  const int e = id & 7;
  const int p = id >> 3;
  const int cnt = counts[e];
  const int m0 = (p >> 2) * 128;
  if (m0 >= cnt) return;
  const int n0 = (p & (NX - 1)) * 128;
  const int off = offsets[e];

  __shared__ alignas(16) unsigned char smem[2][32768];
  unsigned char* smbase = &smem[0][0];

  const int tid = threadIdx.x;
  const int wid = tid >> 6, lane = tid & 63;

  const char* src[4];
  unsigned dst[4];
#pragma unroll
  for (int i = 0; i < 4; ++i) {
    const int c = i * 8 + wid;
    const bool isA = c < 16;
    const int cc = isA ? c : c - 16;
    const int r = cc * 8 + (lane >> 3);
    const int cs = ((lane & 7) * 16) ^ ((r & 7) << 4);
    if (isA) {
      int mrow = m0 + r; if (mrow > cnt - 1) mrow = cnt - 1;
      src[i] = (const char*)A + (size_t)(off + mrow) * KB + cs;
    } else {
      src[i] = (const char*)Bt + (size_t)e * NN * KB + (size_t)(n0 + r) * KB + cs;
    }
    dst[i] = (isA ? 0u : 16384u) + cc * 1024;
  }

  const int wr = wid >> 2, wc = wid & 3;
  const int lr = lane & 15, lk = lane >> 4;

  unsigned aoff[2][2][4], boff[2][2][2];
#pragma unroll
  for (int b = 0; b < 2; ++b)
#pragma unroll
    for (int kk = 0; kk < 2; ++kk) {
#pragma unroll
      for (int mi = 0; mi < 4; ++mi) {
        const int r = wr * 64 + mi * 16 + lr;
        aoff[b][kk][mi] = b * 32768u + r * 128 + ((kk * 64 + lk * 16) ^ ((r & 7) << 4));
      }
#pragma unroll
      for (int ni = 0; ni < 2; ++ni) {
        const int r = wc * 32 + ni * 16 + lr;
        boff[b][kk][ni] = b * 32768u + 16384u + r * 128 + ((kk * 64 + lk * 16) ^ ((r & 7) << 4));
      }
    }

  f32x4 acc[4][2] = {};

#pragma unroll
  for (int i = 0; i < 4; ++i) gll16(src[i], smbase + dst[i]);
#pragma unroll
  for (int i = 0; i < 4; ++i) gll16(src[i] + 128, smbase + 32768u + dst[i]);

  for (int t = 0; t < NT; ++t) {
    if (t + 1 < NT) asm volatile("s_waitcnt vmcnt(4)" ::: "memory");
    else            asm volatile("s_waitcnt vmcnt(0)" ::: "memory");
    __builtin_amdgcn_s_barrier();
    __builtin_amdgcn_sched_barrier(0);
    if (t & 1) mm_step<1>(smbase, aoff, boff, acc);
    else       mm_step<0>(smbase, aoff, boff, acc);
    if (t + 2 < NT) {
      __builtin_amdgcn_s_barrier();
      __builtin_amdgcn_sched_barrier(0);
      const int kb = (t + 2) * 128;
      const unsigned bb = (t & 1) ? 32768u : 0u;
#pragma unroll
      for (int i = 0; i < 4; ++i) gll16(src[i] + kb, smbase + bb + dst[i]);
    }
  }

  const int lq = lane >> 4;
#pragma unroll
  for (int mi = 0; mi < 4; ++mi) {
#pragma unroll
    for (int ni = 0; ni < 2; ++ni) {
      const int n = n0 + wc * 32 + ni * 16 + lr;
      const float bv_ = bias[e * NN + n];
#pragma unroll
      for (int r2 = 0; r2 < 4; ++r2) {
        const int m = m0 + wr * 64 + mi * 16 + lq * 4 + r2;
        if (m < cnt)
          Out[(size_t)(off + m) * DDIM + n] = f2bf(acc[mi][ni][r2] + bv_);
      }
    }
  }
}

// ---------------- combine: out[t] = g0*y[idx0] + g1*y[idx1]  (coalesced, no atomics) ----------------
__global__ __launch_bounds__(256) void k_combine(const unsigned short* __restrict__ yp,
                                                 const int* __restrict__ cidx,
                                                 const float* __restrict__ cgate,
                                                 float* __restrict__ out) {
  const int t = blockIdx.x * 4 + (threadIdx.x >> 6);
  const int lane = threadIdx.x & 63;
  const int i0 = cidx[t * 2], i1 = cidx[t * 2 + 1];
  const float g0 = cgate[t * 2], g1 = cgate[t * 2 + 1];
  us8 a = *(const us8*)(yp + (size_t)i0 * DDIM + lane * 8);
  us8 b = *(const us8*)(yp + (size_t)i1 * DDIM + lane * 8);
  float o[8];
#pragma unroll
  for (int j = 0; j < 8; ++j) {
    const float va = __builtin_bit_cast(float, (unsigned)a[j] << 16);
    const float vb = __builtin_bit_cast(float, (unsigned)b[j] << 16);
    o[j] = g0 * va + g1 * vb;
  }
  float* op = out + (size_t)t * DDIM + lane * 8;
  *(float4*)op = *(float4*)o;
  *(float4*)(op + 4) = *(float4*)(o + 4);
}

extern "C" void kernel_launch(void* const* d_in, const int* in_sizes, int n_in,
                              void* d_out, int out_size, void* d_ws, size_t ws_size,
                              hipStream_t stream) {
  (void)in_sizes; (void)n_in; (void)out_size; (void)ws_size;
  const float* x  = (const float*)d_in[0];
  const float* rw = (const float*)d_in[1];
  const float* rb = (const float*)d_in[2];
  const float* w1 = (const float*)d_in[3];
  const float* b1 = (const float*)d_in[4];
  const float* w2 = (const float*)d_in[5];
  const float* b2 = (const float*)d_in[6];
  float* out = (float*)d_out;
  float* logits = out + (size_t)TTOK * DDIM;

  char* ws = (char*)d_ws;
  unsigned short* xb  = (unsigned short*)(ws + 0);          //  8,388,608
  unsigned short* w1t = (unsigned short*)(ws + 8388608);    // 16,777,216  [E][H][D] bf16
  unsigned short* w2t = (unsigned short*)(ws + 25165824);   // 16,777,216  [E][D][H] bf16
  unsigned short* h   = (unsigned short*)(ws + 41943040);   // 67,108,864  [16384][H] bf16
  int*   toklist = (int*)(ws + 109051904);                  //    262,144
  int*   cidx    = (int*)(ws + 109314048);                  //     65,536
  float* cgate   = (float*)(ws + 109379584);                //     65,536
  int*   counts  = (int*)(ws + 109445120);                  //         32
  int*   offsets = (int*)(ws + 109445152);                  //         32
  // y_packed [16384][512] bf16 ALIASES w1t (dead after k_gemm1, stream-ordered).
  unsigned short* yp = w1t;
  // router scratch ALIASED into h region (consumed before k_gemm1 writes h).
  char* rsc = ws + 41943040;
  short*          texp      = (short*)(rsc + 0);
  unsigned short* tpos      = (unsigned short*)(rsc + 32768);
  float*          tgate     = (float*)(rsc + 65536);
  int*            blockcnt  = (int*)(rsc + 131072);
  int*            blockbase = (int*)(rsc + 139264);

  k_routrans<<<RBLK + 16384, 256, 0, stream>>>(x, rw, rb, logits, xb, texp, tpos, tgate,
                                               blockcnt, w1, w2, w1t, w2t);
  k_offsets<<<1, 512, 0, stream>>>(blockcnt, blockbase, counts, offsets);
  k_scatter<<<TTOK / 256, 256, 0, stream>>>(texp, tpos, tgate, blockbase, offsets,
                                            toklist, cidx, cgate);

  // 1D grids: expert in low 3 bits (expert -> XCD affinity)
  k_gemm1<<<(HDIM / 256) * (TTOK / 128) * NEXP, 512, 0, stream>>>(
      xb, w1t, b1, counts, offsets, toklist, h);
  k_gemm2<<<(DDIM / 128) * (TTOK / 128) * NEXP, 512, 0, stream>>>(
      h, w2t, b2, counts, offsets, yp);
  k_combine<<<TTOK / 4, 256, 0, stream>>>(yp, cidx, cgate, out);
}